// Round 4
// baseline (212.687 us; speedup 1.0000x reference)
//
#include <hip/hip_runtime.h>
#include <hip/hip_bf16.h>

// B=2048, N=512, D=8192.
// Pipeline (NO d_ws, NO atomics; scratch carved from d_out, per-block ownership):
//   1. m_norms:     mm[n]=||m_n||^2 -> p-slot (dead after rescore)
//   2. gemm_coarse: bf16 MFMA dot partials, 128x128 tile, splitK=8 -> m+sd (32 MB).
//                   r12: COALESCED STAGING + 2-AHEAD PIPELINE. r10 proved the
//                   kernel is NOT LDS/VALU-bound (conflicts 6.3M->0, VALU 16->8%,
//                   LDS bytes halved => dur UNCHANGED 58.6us, 4400 cyc/step vs
//                   ~1024 cyc of any pipe's work). Diagnosis: vmem REQUEST-rate
//                   bound -- old map (row t>>2, seg t&3) put lanes at 16B pieces
//                   with 32B gaps: zero coalescing, 4096 16B-requests/CU/step.
//                   New map: thread t -> rows (t>>3, t>>3+64), floats (t&7)*4..+3:
//                   lanes 0-7 cover one row's 128B contiguously -> 8 full lines
//                   per instruction, 8x fewer requests. Identity LDS layout is
//                   bank-uniform for ds_write_b64 AND ds_read_b128 (8/bank = min
//                   service), no swizzle. 2 named regsets (A/B) stage 2 steps
//                   ahead so the pre-ds_write vmcnt waits on loads issued a FULL
//                   step earlier (latency off critical path). Frags bit-identical.
//                   XCD-pinned decode (bid&7 = kc) kept: FETCH 147->41 MB proven.
//   3. rescore:     coarse argmin + margin candidates; exact f32 dots only if >=2
//                   candidates, CANDIDATE-PER-WAVE parallel; winner picked by
//                   index-ordered scan (deterministic under replay).
//   4. ema_scatter: grid (N,8); block (n,s) owns 1024-float slice s; 4-wave
//                   ballot-scan list build (per-wave sublists + prefix merge);
//                   16x/4x batched y-gather, exact-order EMA.

#define Bb 2048
#define Nn 512
#define Dd 8192
#define MARGIN 12.0f
#define KC 8
#define KSTEPS 32   // (Dd/KC)/32

typedef __attribute__((ext_vector_type(4))) float f32x4;
typedef __attribute__((ext_vector_type(8))) short s16x8;
typedef __attribute__((ext_vector_type(2))) unsigned u32x2;

__device__ inline unsigned pack2(float lo, float hi) {
    return __builtin_amdgcn_perm(__float_as_uint(hi), __float_as_uint(lo), 0x07060302u);
}

__device__ inline void st4bf(unsigned short* dst, const float4 v) {
    u32x2 x;
    x[0] = pack2(v.x, v.y);
    x[1] = pack2(v.z, v.w);
    *(u32x2*)dst = x;          // 8B-aligned ds_write_b64
}

__device__ inline void ema4(float4& mcv, float4& scv, const float4 yv) {
#define EMA_C(c) { mcv.c = mcv.c * 0.001f + yv.c * 0.999f; \
                   float d_ = mcv.c - yv.c;                 \
                   scv.c = d_ * d_ * 0.001f + scv.c * 0.999f; }
    EMA_C(x) EMA_C(y) EMA_C(z) EMA_C(w)
#undef EMA_C
}

// ---------------- 1: m row norms ----------------
__global__ __launch_bounds__(256) void m_norms(const float* __restrict__ M,
                                               float* __restrict__ mm) {
    int n = blockIdx.x, t = threadIdx.x;
    const float4* r = (const float4*)(M + (size_t)n * Dd);
    float s = 0.f;
#pragma unroll
    for (int u = 0; u < 8; u++) {
        float4 v = r[t + 256 * u];
        s += v.x * v.x + v.y * v.y + v.z * v.z + v.w * v.w;
    }
    __shared__ float red[256];
    red[t] = s;
    __syncthreads();
    for (int off = 128; off > 0; off >>= 1) {
        if (t < off) red[t] += red[t + off];
        __syncthreads();
    }
    if (t == 0) mm[n] = red[0];
}

// ---------------- 2: coarse bf16 MFMA GEMM (dot only), splitK=8 ----------------
// 1-D grid 512 blocks, 512 threads (8 waves). Decode: kc = bid&7 (XCD-pinned),
// ct = (bid>>3)&3, rt = bid>>5. Tile 128x128, K-chunk 1024 (32 steps of 32).
// Wave w: rows (w&3)*32..+31, cols (w>>2)*64..+63.
// Staging (coalesced): thread t loads rows {t>>3, t>>3+64}, floats (t&7)*4..+3
// per matrix (2x dwordx4, each wave-instr = 8 contiguous 128B lines); pack ->
// 2x ds_write_b64 each matrix at identity LDS offset. Double-buffered LDS,
// double register set (2-step-ahead loads).
__global__ __launch_bounds__(512, 4) void gemm_coarse(const float* __restrict__ Y,
                                                      const float* __restrict__ M,
                                                      float* __restrict__ part) {
    __shared__ __align__(16) unsigned short As[2][128 * 32];
    __shared__ __align__(16) unsigned short Bs[2][128 * 32];
    const int t = threadIdx.x;
    const int lane = t & 63;
    const int w = t >> 6;

    const int bid = blockIdx.x;
    const int kc = bid & 7;          // one kc chunk per XCD
    const int ct = (bid >> 3) & 3;
    const int rt = bid >> 5;

    const size_t ybase = (size_t)rt * 128 * Dd + (size_t)kc * (KSTEPS * 32);
    const size_t mbase = (size_t)ct * 128 * Dd + (size_t)kc * (KSTEPS * 32);

    // coalesced staging geometry
    const int rL = t >> 3;                 // rows rL and rL+64
    const int g4 = (t & 7) * 4;            // float col within 32-float panel
    const float* gA0 = Y + ybase + (size_t)rL * Dd + g4;
    const float* gB0 = M + mbase + (size_t)rL * Dd + g4;
    const int dst0 = rL * 32 + g4;         // bf16 elem offset (identity layout)

    const int wr0 = (w & 3) * 32, wc0 = (w >> 2) * 64;
    const int l15 = lane & 15, quad = lane >> 4;

    f32x4 acc[2][4];
#pragma unroll
    for (int i = 0; i < 2; i++)
#pragma unroll
        for (int j = 0; j < 4; j++) acc[i][j] = (f32x4)(0.0f);

    // two named staging register sets (static, never runtime-indexed)
    float4 aA0, aA1, aB0, aB1;     // set A
    float4 bA0, bA1, bB0, bB1;     // set B
    const size_t rowskip = (size_t)64 * Dd;

    auto loadsA = [&](int step) {
        const float* pa = gA0 + step * 32;
        const float* pb = gB0 + step * 32;
        aA0 = *(const float4*)pa;  aA1 = *(const float4*)(pa + rowskip);
        aB0 = *(const float4*)pb;  aB1 = *(const float4*)(pb + rowskip);
    };
    auto loadsB = [&](int step) {
        const float* pa = gA0 + step * 32;
        const float* pb = gB0 + step * 32;
        bA0 = *(const float4*)pa;  bA1 = *(const float4*)(pa + rowskip);
        bB0 = *(const float4*)pb;  bB1 = *(const float4*)(pb + rowskip);
    };
    auto writesA = [&](int buf) {
        st4bf(&As[buf][dst0],        aA0);
        st4bf(&As[buf][dst0 + 2048], aA1);    // +64 rows * 32 elems
        st4bf(&Bs[buf][dst0],        aB0);
        st4bf(&Bs[buf][dst0 + 2048], aB1);
    };
    auto writesB = [&](int buf) {
        st4bf(&As[buf][dst0],        bA0);
        st4bf(&As[buf][dst0 + 2048], bA1);
        st4bf(&Bs[buf][dst0],        bB0);
        st4bf(&Bs[buf][dst0 + 2048], bB1);
    };
    auto compute = [&](int buf) {
        s16x8 fa[2], fb[4];
#pragma unroll
        for (int ta = 0; ta < 2; ta++)
            fa[ta] = *(const s16x8*)(&As[buf][(wr0 + ta * 16 + l15) * 32 + quad * 8]);
#pragma unroll
        for (int tb = 0; tb < 4; tb++)
            fb[tb] = *(const s16x8*)(&Bs[buf][(wc0 + tb * 16 + l15) * 32 + quad * 8]);
#pragma unroll
        for (int i = 0; i < 2; i++)
#pragma unroll
            for (int j = 0; j < 4; j++)
                acc[i][j] = __builtin_amdgcn_mfma_f32_16x16x32_bf16(fa[i], fb[j], acc[i][j], 0, 0, 0);
    };

    // 2-ahead pipeline: at each ds_write, the source loads were issued one full
    // step earlier (vmcnt wait covers a whole compute phase). One barrier per
    // buffer handoff; steady state keeps <=8 loads in flight.
    loadsA(0);
    loadsB(1);
    writesA(0);                      // waits loadsA only (counted vmcnt)
    __syncthreads();
    for (int step = 0; step < KSTEPS; step += 2) {
        if (step + 2 < KSTEPS) loadsA(step + 2);
        compute(0);                  // step
        writesB(1);                  // step+1 data, loaded last iteration
        __syncthreads();
        if (step + 3 < KSTEPS) loadsB(step + 3);
        compute(1);                  // step+1
        if (step + 2 < KSTEPS) writesA(0);   // step+2 data
        __syncthreads();
    }

    // store partials; C/D layout: col = lane&15, row = quad*4 + reg
    float* P = part + (size_t)kc * (Bb * Nn);
#pragma unroll
    for (int i = 0; i < 2; i++) {
        int rg = rt * 128 + wr0 + i * 16 + quad * 4;
#pragma unroll
        for (int j = 0; j < 4; j++) {
            int cg = ct * 128 + wc0 + j * 16 + l15;
#pragma unroll
            for (int r = 0; r < 4; r++)
                P[(size_t)(rg + r) * Nn + cg] = acc[i][j][r];
        }
    }
}

// ---------------- 3: coarse argmin + wave-parallel exact rescore ----------------
__global__ __launch_bounds__(256) void rescore(const float* __restrict__ Y,
                                               const float* __restrict__ M,
                                               const float* __restrict__ part,
                                               const float* __restrict__ mm,
                                               float* __restrict__ assignF) {
    __shared__ float redW[4];
    __shared__ int candList[Nn];
    __shared__ float candD2[Nn];
    __shared__ int candCnt;
    int b = blockIdx.x, t = threadIdx.x, lane = t & 63, w = t >> 6;
    if (t == 0) candCnt = 0;

    int c0 = t, c1 = t + 256;
    float dot0 = 0.f, dot1 = 0.f;
#pragma unroll
    for (int k = 0; k < KC; k++) {
        dot0 += part[(size_t)k * (Bb * Nn) + (size_t)b * Nn + c0];
        dot1 += part[(size_t)k * (Bb * Nn) + (size_t)b * Nn + c1];
    }
    float d0 = mm[c0] - 2.0f * dot0;
    float d1 = mm[c1] - 2.0f * dot1;

    float mn = fminf(d0, d1);
#pragma unroll
    for (int off = 32; off > 0; off >>= 1) mn = fminf(mn, __shfl_xor(mn, off));
    if (lane == 0) redW[w] = mn;
    __syncthreads();
    float thresh = fminf(fminf(redW[0], redW[1]), fminf(redW[2], redW[3])) + MARGIN;

    if (d0 <= thresh) candList[atomicAdd(&candCnt, 1)] = c0;
    if (d1 <= thresh) candList[atomicAdd(&candCnt, 1)] = c1;
    __syncthreads();
    int ncand = candCnt;

    if (ncand == 1) {                 // uncontested coarse winner: exact dot unnecessary
        if (t == 0) assignF[b] = (float)candList[0];
        return;
    }

    // each wave handles candidates j = w, w+4, ... (full-row dot per wave)
    const float4* yr = (const float4*)(Y + (size_t)b * Dd);
    for (int j = w; j < ncand; j += 4) {
        int c = candList[j];
        const float4* mr = (const float4*)(M + (size_t)c * Dd);
        float p = 0.f;
#pragma unroll 8
        for (int u = 0; u < 32; u++) {
            float4 yv = yr[u * 64 + lane];
            float4 mv = mr[u * 64 + lane];
            p += yv.x * mv.x + yv.y * mv.y + yv.z * mv.z + yv.w * mv.w;
        }
#pragma unroll
        for (int off = 32; off > 0; off >>= 1) p += __shfl_xor(p, off);
        if (lane == 0) candD2[j] = mm[c] - 2.0f * p;
    }
    __syncthreads();

    if (t == 0) {       // index-ordered scan: deterministic regardless of list order
        float bestV = 3.4e38f;
        int bestI = 0x3fffffff;
        for (int j = 0; j < ncand; j++) {
            float d2e = candD2[j];
            int c = candList[j];
            if (d2e < bestV || (d2e == bestV && c < bestI)) { bestV = d2e; bestI = c; }
        }
        assignF[b] = (float)bestI;
    }
}

// ---------------- 4: per-cluster sequential EMA, D-sliced x8, 4-wave list build --
__global__ __launch_bounds__(256) void ema_scatter(const float* __restrict__ Y,
                                                   const float* __restrict__ M0,
                                                   const float* __restrict__ SD0,
                                                   const float* __restrict__ P0,
                                                   const float* __restrict__ assignF,
                                                   float* __restrict__ m_out,
                                                   float* __restrict__ sd_out,
                                                   float* __restrict__ p_out) {
    __shared__ int lst[Bb];
    __shared__ int cnt4[4];
    int n = blockIdx.x, s = blockIdx.y, t = threadIdx.x, lane = t & 63, w = t >> 6;

    // all 4 waves scan: wave w owns u-range [w*8, w*8+8) -> ordered sublist;
    // merge via prefix of per-wave counts (list identical to serial scan).
    int eqf[8], myidx[8];
    int cntW = 0;
#pragma unroll
    for (int k = 0; k < 8; k++) {
        int u = w * 8 + k;
        int zi = (int)assignF[u * 64 + lane];
        int eq = (zi == n) ? 1 : 0;
        unsigned long long mask = __ballot(eq != 0);
        eqf[k] = eq;
        myidx[k] = cntW + (int)__popcll(mask & ((1ull << lane) - 1ull));
        cntW += (int)__popcll(mask);
    }
    if (lane == 0) cnt4[w] = cntW;
    __syncthreads();
    int off0 = 0;
#pragma unroll
    for (int q = 0; q < 4; q++) off0 += (q < w) ? cnt4[q] : 0;
    int cnt = cnt4[0] + cnt4[1] + cnt4[2] + cnt4[3];
#pragma unroll
    for (int k = 0; k < 8; k++)
        if (eqf[k]) lst[off0 + myidx[k]] = (w * 8 + k) * 64 + lane;
    if (t == 0 && s == 0) p_out[n] = P0[n] + (float)cnt;
    __syncthreads();

    size_t off = (size_t)n * Dd + (size_t)s * 1024;
    float4 mc = *(const float4*)(M0 + off + 4 * t);
    float4 sc = *(const float4*)(SD0 + off + 4 * t);

    int j = 0;
    for (; j + 16 <= cnt; j += 16) {     // 16x batched gathers, exact-order EMA
        float4 yv[16];
#pragma unroll
        for (int q = 0; q < 16; q++)
            yv[q] = *(const float4*)(Y + (size_t)lst[j + q] * Dd + (size_t)s * 1024 + 4 * t);
#pragma unroll
        for (int q = 0; q < 16; q++) ema4(mc, sc, yv[q]);
    }
    for (; j + 4 <= cnt; j += 4) {       // 4x batch tier (avg cluster size ~4)
        float4 yv[4];
#pragma unroll
        for (int q = 0; q < 4; q++)
            yv[q] = *(const float4*)(Y + (size_t)lst[j + q] * Dd + (size_t)s * 1024 + 4 * t);
#pragma unroll
        for (int q = 0; q < 4; q++) ema4(mc, sc, yv[q]);
    }
    for (; j < cnt; j++) {
        float4 yv = *(const float4*)(Y + (size_t)lst[j] * Dd + (size_t)s * 1024 + 4 * t);
        ema4(mc, sc, yv);
    }

    *(float4*)(m_out + off + 4 * t) = mc;
    *(float4*)(sd_out + off + 4 * t) = sc;
}

extern "C" void kernel_launch(void* const* d_in, const int* in_sizes, int n_in,
                              void* d_out, int out_size, void* d_ws, size_t ws_size,
                              hipStream_t stream) {
    const float* y  = (const float*)d_in[0];
    const float* m  = (const float*)d_in[1];
    const float* sd = (const float*)d_in[2];
    const float* p  = (const float*)d_in[3];

    float* out     = (float*)d_out;
    float* m_out   = out;                       // partials k=0..3 live here pre-rescore
    float* sd_out  = out + 4194304;             // partials k=4..7 live here pre-rescore
    float* p_out   = out + 8388608;             // also: mm norms (dead after rescore)
    float* assignF = out + 8389120;
    float* part    = out;                       // 8 x 1M floats = m+sd regions exactly

    m_norms    <<<Nn, 256, 0, stream>>>(m, p_out);
    gemm_coarse<<<dim3(512), 512, 0, stream>>>(y, m, part);
    rescore    <<<Bb, 256, 0, stream>>>(y, m, part, p_out, assignF);
    ema_scatter<<<dim3(Nn, 8), 256, 0, stream>>>(y, m, sd, p, assignF, m_out, sd_out, p_out);
}

// Round 5
// 210.922 us; speedup vs baseline: 1.0084x; 1.0084x over previous
//
#include <hip/hip_runtime.h>
#include <hip/hip_bf16.h>

// B=2048, N=512, D=8192.
// Pipeline (NO d_ws, NO atomics; scratch carved from d_out, per-block ownership):
//   1. m_norms:     mm[n]=||m_n||^2 -> p-slot (dead after rescore)
//   2. gemm_coarse: bf16 MFMA dot partials, 128x128 tile, splitK=8 -> m+sd (32 MB).
//                   r13: RAW BARRIER + COUNTED VMCNT (T4). r9/r10/r12 each fixed a
//                   predicted counter (FETCH -72%, conflicts->0, VALU halved,
//                   coalesced requests) with ZERO time change: every pipe <=16%
//                   busy, 4400 cyc/step vs ~1900 cyc work => serialization stall.
//                   Root cause: __syncthreads == s_waitcnt vmcnt(0) lgkmcnt(0) +
//                   s_barrier -- the vmcnt(0) DRAIN killed the 2-ahead pipeline
//                   every step (no load survives a barrier). Now: ds_writes made
//                   visible with lgkmcnt(0) only, then RAW s_barrier; compiler
//                   emits counted vmcnt(4) before regset use, so 8 staging loads
//                   stay in flight ACROSS barriers (m201/m218 mechanism).
//                   Geometry unchanged from r12: coalesced staging (thread t ->
//                   rows {t>>3, t>>3+64}, floats (t&7)*4..+3), identity LDS
//                   layout, 2 named regsets, XCD-pinned kc=bid&7.
//   3. rescore:     coarse argmin + margin candidates; exact f32 dots only if >=2
//                   candidates, CANDIDATE-PER-WAVE parallel; winner picked by
//                   index-ordered scan (deterministic under replay).
//   4. ema_scatter: grid (N,8); block (n,s) owns 1024-float slice s; 4-wave
//                   ballot-scan list build (per-wave sublists + prefix merge);
//                   16x/4x batched y-gather, exact-order EMA.

#define Bb 2048
#define Nn 512
#define Dd 8192
#define MARGIN 12.0f
#define KC 8
#define KSTEPS 32   // (Dd/KC)/32

typedef __attribute__((ext_vector_type(4))) float f32x4;
typedef __attribute__((ext_vector_type(8))) short s16x8;
typedef __attribute__((ext_vector_type(2))) unsigned u32x2;

__device__ inline unsigned pack2(float lo, float hi) {
    return __builtin_amdgcn_perm(__float_as_uint(hi), __float_as_uint(lo), 0x07060302u);
}

__device__ inline void st4bf(unsigned short* dst, const float4 v) {
    u32x2 x;
    x[0] = pack2(v.x, v.y);
    x[1] = pack2(v.z, v.w);
    *(u32x2*)dst = x;          // 8B-aligned ds_write_b64
}

__device__ inline void ema4(float4& mcv, float4& scv, const float4 yv) {
#define EMA_C(c) { mcv.c = mcv.c * 0.001f + yv.c * 0.999f; \
                   float d_ = mcv.c - yv.c;                 \
                   scv.c = d_ * d_ * 0.001f + scv.c * 0.999f; }
    EMA_C(x) EMA_C(y) EMA_C(z) EMA_C(w)
#undef EMA_C
}

// ---------------- 1: m row norms ----------------
__global__ __launch_bounds__(256) void m_norms(const float* __restrict__ M,
                                               float* __restrict__ mm) {
    int n = blockIdx.x, t = threadIdx.x;
    const float4* r = (const float4*)(M + (size_t)n * Dd);
    float s = 0.f;
#pragma unroll
    for (int u = 0; u < 8; u++) {
        float4 v = r[t + 256 * u];
        s += v.x * v.x + v.y * v.y + v.z * v.z + v.w * v.w;
    }
    __shared__ float red[256];
    red[t] = s;
    __syncthreads();
    for (int off = 128; off > 0; off >>= 1) {
        if (t < off) red[t] += red[t + off];
        __syncthreads();
    }
    if (t == 0) mm[n] = red[0];
}

// ---------------- 2: coarse bf16 MFMA GEMM (dot only), splitK=8 ----------------
// 1-D grid 512 blocks, 512 threads (8 waves). Decode: kc = bid&7 (XCD-pinned),
// ct = (bid>>3)&3, rt = bid>>5. Tile 128x128, K-chunk 1024 (32 steps of 32).
// Wave w: rows (w&3)*32..+31, cols (w>>2)*64..+63.
// Staging (coalesced): thread t loads rows {t>>3, t>>3+64}, floats (t&7)*4..+3
// per matrix (2x dwordx4, each wave-instr = 8 contiguous 128B lines); pack ->
// 2x ds_write_b64 each matrix at identity LDS offset. Double-buffered LDS,
// double register set (2-step-ahead loads), RAW barriers (loads span barriers).
__global__ __launch_bounds__(512, 4) void gemm_coarse(const float* __restrict__ Y,
                                                      const float* __restrict__ M,
                                                      float* __restrict__ part) {
    __shared__ __align__(16) unsigned short As[2][128 * 32];
    __shared__ __align__(16) unsigned short Bs[2][128 * 32];
    const int t = threadIdx.x;
    const int lane = t & 63;
    const int w = t >> 6;

    const int bid = blockIdx.x;
    const int kc = bid & 7;          // one kc chunk per XCD
    const int ct = (bid >> 3) & 3;
    const int rt = bid >> 5;

    const size_t ybase = (size_t)rt * 128 * Dd + (size_t)kc * (KSTEPS * 32);
    const size_t mbase = (size_t)ct * 128 * Dd + (size_t)kc * (KSTEPS * 32);

    // coalesced staging geometry
    const int rL = t >> 3;                 // rows rL and rL+64
    const int g4 = (t & 7) * 4;            // float col within 32-float panel
    const float* gA0 = Y + ybase + (size_t)rL * Dd + g4;
    const float* gB0 = M + mbase + (size_t)rL * Dd + g4;
    const int dst0 = rL * 32 + g4;         // bf16 elem offset (identity layout)

    const int wr0 = (w & 3) * 32, wc0 = (w >> 2) * 64;
    const int l15 = lane & 15, quad = lane >> 4;

    f32x4 acc[2][4];
#pragma unroll
    for (int i = 0; i < 2; i++)
#pragma unroll
        for (int j = 0; j < 4; j++) acc[i][j] = (f32x4)(0.0f);

    // two named staging register sets (static, never runtime-indexed)
    float4 aA0, aA1, aB0, aB1;     // set A
    float4 bA0, bA1, bB0, bB1;     // set B
    const size_t rowskip = (size_t)64 * Dd;

    auto loadsA = [&](int step) {
        const float* pa = gA0 + step * 32;
        const float* pb = gB0 + step * 32;
        aA0 = *(const float4*)pa;  aA1 = *(const float4*)(pa + rowskip);
        aB0 = *(const float4*)pb;  aB1 = *(const float4*)(pb + rowskip);
    };
    auto loadsB = [&](int step) {
        const float* pa = gA0 + step * 32;
        const float* pb = gB0 + step * 32;
        bA0 = *(const float4*)pa;  bA1 = *(const float4*)(pa + rowskip);
        bB0 = *(const float4*)pb;  bB1 = *(const float4*)(pb + rowskip);
    };
    auto writesA = [&](int buf) {
        st4bf(&As[buf][dst0],        aA0);
        st4bf(&As[buf][dst0 + 2048], aA1);    // +64 rows * 32 elems
        st4bf(&Bs[buf][dst0],        aB0);
        st4bf(&Bs[buf][dst0 + 2048], aB1);
    };
    auto writesB = [&](int buf) {
        st4bf(&As[buf][dst0],        bA0);
        st4bf(&As[buf][dst0 + 2048], bA1);
        st4bf(&Bs[buf][dst0],        bB0);
        st4bf(&Bs[buf][dst0 + 2048], bB1);
    };
    auto compute = [&](int buf) {
        s16x8 fa[2], fb[4];
#pragma unroll
        for (int ta = 0; ta < 2; ta++)
            fa[ta] = *(const s16x8*)(&As[buf][(wr0 + ta * 16 + l15) * 32 + quad * 8]);
#pragma unroll
        for (int tb = 0; tb < 4; tb++)
            fb[tb] = *(const s16x8*)(&Bs[buf][(wc0 + tb * 16 + l15) * 32 + quad * 8]);
#pragma unroll
        for (int i = 0; i < 2; i++)
#pragma unroll
            for (int j = 0; j < 4; j++)
                acc[i][j] = __builtin_amdgcn_mfma_f32_16x16x32_bf16(fa[i], fb[j], acc[i][j], 0, 0, 0);
    };

    // RAW barrier: ds_writes made visible with lgkmcnt(0) ONLY -- staging loads
    // target VGPRs, so no vmem drain is needed for cross-wave correctness.
    // Compiler emits counted vmcnt(4) before each regset's pack (it tracks the
    // load->use chain), so up to 8 staging loads stay in flight ACROSS barriers.
#define BARRIER() do {                                          \
        asm volatile("s_waitcnt lgkmcnt(0)" ::: "memory");      \
        __builtin_amdgcn_s_barrier();                           \
    } while (0)

    // 2-ahead pipeline: at each ds_write, the source loads were issued one full
    // step earlier (vmcnt wait covers a whole compute phase).
    loadsA(0);
    loadsB(1);
    writesA(0);                      // waits loadsA only (counted vmcnt(4))
    BARRIER();
    for (int step = 0; step < KSTEPS; step += 2) {
        if (step + 2 < KSTEPS) loadsA(step + 2);
        compute(0);                  // step
        writesB(1);                  // step+1 data, loaded last iteration
        BARRIER();
        if (step + 3 < KSTEPS) loadsB(step + 3);
        compute(1);                  // step+1
        if (step + 2 < KSTEPS) writesA(0);   // step+2 data
        BARRIER();
    }
#undef BARRIER

    // store partials; C/D layout: col = lane&15, row = quad*4 + reg
    float* P = part + (size_t)kc * (Bb * Nn);
#pragma unroll
    for (int i = 0; i < 2; i++) {
        int rg = rt * 128 + wr0 + i * 16 + quad * 4;
#pragma unroll
        for (int j = 0; j < 4; j++) {
            int cg = ct * 128 + wc0 + j * 16 + l15;
#pragma unroll
            for (int r = 0; r < 4; r++)
                P[(size_t)(rg + r) * Nn + cg] = acc[i][j][r];
        }
    }
}

// ---------------- 3: coarse argmin + wave-parallel exact rescore ----------------
__global__ __launch_bounds__(256) void rescore(const float* __restrict__ Y,
                                               const float* __restrict__ M,
                                               const float* __restrict__ part,
                                               const float* __restrict__ mm,
                                               float* __restrict__ assignF) {
    __shared__ float redW[4];
    __shared__ int candList[Nn];
    __shared__ float candD2[Nn];
    __shared__ int candCnt;
    int b = blockIdx.x, t = threadIdx.x, lane = t & 63, w = t >> 6;
    if (t == 0) candCnt = 0;

    int c0 = t, c1 = t + 256;
    float dot0 = 0.f, dot1 = 0.f;
#pragma unroll
    for (int k = 0; k < KC; k++) {
        dot0 += part[(size_t)k * (Bb * Nn) + (size_t)b * Nn + c0];
        dot1 += part[(size_t)k * (Bb * Nn) + (size_t)b * Nn + c1];
    }
    float d0 = mm[c0] - 2.0f * dot0;
    float d1 = mm[c1] - 2.0f * dot1;

    float mn = fminf(d0, d1);
#pragma unroll
    for (int off = 32; off > 0; off >>= 1) mn = fminf(mn, __shfl_xor(mn, off));
    if (lane == 0) redW[w] = mn;
    __syncthreads();
    float thresh = fminf(fminf(redW[0], redW[1]), fminf(redW[2], redW[3])) + MARGIN;

    if (d0 <= thresh) candList[atomicAdd(&candCnt, 1)] = c0;
    if (d1 <= thresh) candList[atomicAdd(&candCnt, 1)] = c1;
    __syncthreads();
    int ncand = candCnt;

    if (ncand == 1) {                 // uncontested coarse winner: exact dot unnecessary
        if (t == 0) assignF[b] = (float)candList[0];
        return;
    }

    // each wave handles candidates j = w, w+4, ... (full-row dot per wave)
    const float4* yr = (const float4*)(Y + (size_t)b * Dd);
    for (int j = w; j < ncand; j += 4) {
        int c = candList[j];
        const float4* mr = (const float4*)(M + (size_t)c * Dd);
        float p = 0.f;
#pragma unroll 8
        for (int u = 0; u < 32; u++) {
            float4 yv = yr[u * 64 + lane];
            float4 mv = mr[u * 64 + lane];
            p += yv.x * mv.x + yv.y * mv.y + yv.z * mv.z + yv.w * mv.w;
        }
#pragma unroll
        for (int off = 32; off > 0; off >>= 1) p += __shfl_xor(p, off);
        if (lane == 0) candD2[j] = mm[c] - 2.0f * p;
    }
    __syncthreads();

    if (t == 0) {       // index-ordered scan: deterministic regardless of list order
        float bestV = 3.4e38f;
        int bestI = 0x3fffffff;
        for (int j = 0; j < ncand; j++) {
            float d2e = candD2[j];
            int c = candList[j];
            if (d2e < bestV || (d2e == bestV && c < bestI)) { bestV = d2e; bestI = c; }
        }
        assignF[b] = (float)bestI;
    }
}

// ---------------- 4: per-cluster sequential EMA, D-sliced x8, 4-wave list build --
__global__ __launch_bounds__(256) void ema_scatter(const float* __restrict__ Y,
                                                   const float* __restrict__ M0,
                                                   const float* __restrict__ SD0,
                                                   const float* __restrict__ P0,
                                                   const float* __restrict__ assignF,
                                                   float* __restrict__ m_out,
                                                   float* __restrict__ sd_out,
                                                   float* __restrict__ p_out) {
    __shared__ int lst[Bb];
    __shared__ int cnt4[4];
    int n = blockIdx.x, s = blockIdx.y, t = threadIdx.x, lane = t & 63, w = t >> 6;

    // all 4 waves scan: wave w owns u-range [w*8, w*8+8) -> ordered sublist;
    // merge via prefix of per-wave counts (list identical to serial scan).
    int eqf[8], myidx[8];
    int cntW = 0;
#pragma unroll
    for (int k = 0; k < 8; k++) {
        int u = w * 8 + k;
        int zi = (int)assignF[u * 64 + lane];
        int eq = (zi == n) ? 1 : 0;
        unsigned long long mask = __ballot(eq != 0);
        eqf[k] = eq;
        myidx[k] = cntW + (int)__popcll(mask & ((1ull << lane) - 1ull));
        cntW += (int)__popcll(mask);
    }
    if (lane == 0) cnt4[w] = cntW;
    __syncthreads();
    int off0 = 0;
#pragma unroll
    for (int q = 0; q < 4; q++) off0 += (q < w) ? cnt4[q] : 0;
    int cnt = cnt4[0] + cnt4[1] + cnt4[2] + cnt4[3];
#pragma unroll
    for (int k = 0; k < 8; k++)
        if (eqf[k]) lst[off0 + myidx[k]] = (w * 8 + k) * 64 + lane;
    if (t == 0 && s == 0) p_out[n] = P0[n] + (float)cnt;
    __syncthreads();

    size_t off = (size_t)n * Dd + (size_t)s * 1024;
    float4 mc = *(const float4*)(M0 + off + 4 * t);
    float4 sc = *(const float4*)(SD0 + off + 4 * t);

    int j = 0;
    for (; j + 16 <= cnt; j += 16) {     // 16x batched gathers, exact-order EMA
        float4 yv[16];
#pragma unroll
        for (int q = 0; q < 16; q++)
            yv[q] = *(const float4*)(Y + (size_t)lst[j + q] * Dd + (size_t)s * 1024 + 4 * t);
#pragma unroll
        for (int q = 0; q < 16; q++) ema4(mc, sc, yv[q]);
    }
    for (; j + 4 <= cnt; j += 4) {       // 4x batch tier (avg cluster size ~4)
        float4 yv[4];
#pragma unroll
        for (int q = 0; q < 4; q++)
            yv[q] = *(const float4*)(Y + (size_t)lst[j + q] * Dd + (size_t)s * 1024 + 4 * t);
#pragma unroll
        for (int q = 0; q < 4; q++) ema4(mc, sc, yv[q]);
    }
    for (; j < cnt; j++) {
        float4 yv = *(const float4*)(Y + (size_t)lst[j] * Dd + (size_t)s * 1024 + 4 * t);
        ema4(mc, sc, yv);
    }

    *(float4*)(m_out + off + 4 * t) = mc;
    *(float4*)(sd_out + off + 4 * t) = sc;
}

extern "C" void kernel_launch(void* const* d_in, const int* in_sizes, int n_in,
                              void* d_out, int out_size, void* d_ws, size_t ws_size,
                              hipStream_t stream) {
    const float* y  = (const float*)d_in[0];
    const float* m  = (const float*)d_in[1];
    const float* sd = (const float*)d_in[2];
    const float* p  = (const float*)d_in[3];

    float* out     = (float*)d_out;
    float* m_out   = out;                       // partials k=0..3 live here pre-rescore
    float* sd_out  = out + 4194304;             // partials k=4..7 live here pre-rescore
    float* p_out   = out + 8388608;             // also: mm norms (dead after rescore)
    float* assignF = out + 8389120;
    float* part    = out;                       // 8 x 1M floats = m+sd regions exactly

    m_norms    <<<Nn, 256, 0, stream>>>(m, p_out);
    gemm_coarse<<<dim3(512), 512, 0, stream>>>(y, m, part);
    rescore    <<<Bb, 256, 0, stream>>>(y, m, part, p_out, assignF);
    ema_scatter<<<dim3(Nn, 8), 256, 0, stream>>>(y, m, sd, p, assignF, m_out, sd_out, p_out);
}